// Round 7
// baseline (122.510 us; speedup 1.0000x reference)
//
#include <hip/hip_runtime.h>
#include <hip/hip_bf16.h>

#define ATT_SCALE 0.17677669529663687f   // 1/sqrt(32)

typedef __attribute__((ext_vector_type(8))) short short8v;
typedef __attribute__((ext_vector_type(4))) float f32x4;

__device__ __forceinline__ short f2bf(float f) {
    unsigned u = __builtin_bit_cast(unsigned, f);
    u = u + 0x7fffu + ((u >> 16) & 1u);   // RNE
    return (short)(u >> 16);
}
__device__ __forceinline__ float bf2f(short s) {
    unsigned u = ((unsigned)(unsigned short)s) << 16;
    return __builtin_bit_cast(float, u);
}
__device__ __forceinline__ unsigned pk2(float lo, float hi) {
    return (unsigned)(unsigned short)f2bf(lo) |
           ((unsigned)(unsigned short)f2bf(hi) << 16);
}

// ---------------------------------------------------------------------------
// K0: one-time weight conversion. wbf = bf16{Wq*scale, Wk, Wv, Wg};
// wbbf = bf16 Wb; Wo -> hi/lo bf16 split.
// ---------------------------------------------------------------------------
__global__ __launch_bounds__(256) void k_wprep(
    const float* __restrict__ Wq, const float* __restrict__ Wk,
    const float* __restrict__ Wv, const float* __restrict__ Wg,
    const float* __restrict__ Wb, const float* __restrict__ Wo,
    unsigned short* __restrict__ wbf, unsigned short* __restrict__ wbbf,
    unsigned short* __restrict__ wohi, unsigned short* __restrict__ wolo)
{
    int idx = blockIdx.x * 256 + threadIdx.x;
    if (idx < 65536) {
        int m = idx >> 14, e = idx & 16383;
        float v;
        if (m == 0)      v = Wq[e] * ATT_SCALE;
        else if (m == 1) v = Wk[e];
        else if (m == 2) v = Wv[e];
        else             v = Wg[e];
        wbf[idx] = (unsigned short)f2bf(v);
    } else if (idx < 66048) {
        int e = idx - 65536;
        wbbf[e] = (unsigned short)f2bf(Wb[e]);
    } else if (idx < 82432) {
        int e = idx - 66048;
        float w = Wo[e];
        short hv = f2bf(w);
        wohi[e] = (unsigned short)hv;
        wolo[e] = (unsigned short)f2bf(w - bf2f(hv));
    }
}

// ---------------------------------------------------------------------------
// KA: LN + projections + bias. 512 threads = 8 waves, block = 128 positions.
// Wave tile 64 rows x 32 cols; wc (0..3) == head. One barrier total.
// q/k written bf16 head-major [h][pos][32]; V written TRANSPOSED bf16
// VT[h][x][d=32][y=256] (attention B-fragment-ready). g fp32 head-major.
// bias fp32 natural [h][j][k].
// ---------------------------------------------------------------------------
__global__ __launch_bounds__(512, 4) void k_lnproj(
    const float* __restrict__ z, const float* __restrict__ lnw,
    const float* __restrict__ lnb,
    const unsigned short* __restrict__ wbf, const unsigned short* __restrict__ wbbf,
    const float* __restrict__ bg,
    unsigned short* __restrict__ q_o, unsigned short* __restrict__ k_o,
    unsigned short* __restrict__ vt_o, float* __restrict__ g_o,
    float* __restrict__ bN)
{
    __shared__ __align__(16) short zn[128][136];       // 34.8 KB, persists
    __shared__ __align__(16) short wstg[8][32][40];    // 20.5 KB, wave-private

    const int tid  = threadIdx.x;
    const int lane = tid & 63;
    const int wave = tid >> 6;
    const int l15  = lane & 15;
    const int g    = lane >> 4;
    const int wr   = wave >> 2;       // row half (0..1)
    const int wc   = wave & 3;        // col quarter == head (0..3)
    const long p0  = (long)blockIdx.x * 128;
    const int xq   = (int)(p0 >> 8);
    const int y0   = (int)(p0 & 255);

    // ---- LN: thread = (row, quarter) ----
    {
        const int r = tid >> 2, q4 = tid & 3;
        const float* zrow = z + (p0 + r) * 128 + q4 * 32;
        float4 xv[8];
        float s1 = 0.f, s2 = 0.f;
#pragma unroll
        for (int m = 0; m < 8; ++m) {
            xv[m] = *(const float4*)(zrow + m * 4);
            s1 += xv[m].x + xv[m].y + xv[m].z + xv[m].w;
            s2 += xv[m].x * xv[m].x + xv[m].y * xv[m].y +
                  xv[m].z * xv[m].z + xv[m].w * xv[m].w;
        }
        s1 += __shfl_xor(s1, 1); s2 += __shfl_xor(s2, 1);
        s1 += __shfl_xor(s1, 2); s2 += __shfl_xor(s2, 2);
        float mu  = s1 * 0.0078125f;
        float inv = rsqrtf(s2 * 0.0078125f - mu * mu + 1e-5f);
#pragma unroll
        for (int mm = 0; mm < 4; ++mm) {
            float4 a = xv[2 * mm], b = xv[2 * mm + 1];
            const float* wp = lnw + q4 * 32 + mm * 8;
            const float* bp = lnb + q4 * 32 + mm * 8;
            float4 w0 = *(const float4*)wp, w1 = *(const float4*)(wp + 4);
            float4 b0 = *(const float4*)bp, b1 = *(const float4*)(bp + 4);
            uint4 uu;
            uu.x = pk2((a.x - mu) * inv * w0.x + b0.x, (a.y - mu) * inv * w0.y + b0.y);
            uu.y = pk2((a.z - mu) * inv * w0.z + b0.z, (a.w - mu) * inv * w0.w + b0.w);
            uu.z = pk2((b.x - mu) * inv * w1.x + b1.x, (b.y - mu) * inv * w1.y + b1.y);
            uu.w = pk2((b.z - mu) * inv * w1.z + b1.z, (b.w - mu) * inv * w1.w + b1.w);
            *(uint4*)&zn[r][q4 * 32 + mm * 8] = uu;
        }
    }
    __syncthreads();   // the only block-wide barrier

    // ---- pair bias (waves with wc==0; lanes l15<4 write head l15) ----
    if (wc == 0) {
        const unsigned short* wbp = wbbf + (l15 & 3) * 128;
        short8v wb[4];
#pragma unroll
        for (int ks = 0; ks < 4; ++ks)
            wb[ks] = *(const short8v*)(wbp + ks * 32 + g * 8);
        f32x4 bacc[4];
#pragma unroll
        for (int rt = 0; rt < 4; ++rt) bacc[rt] = (f32x4){0.f, 0.f, 0.f, 0.f};
#pragma unroll
        for (int ks = 0; ks < 4; ++ks)
#pragma unroll
            for (int rt = 0; rt < 4; ++rt) {
                short8v a = *(const short8v*)&zn[wr * 64 + rt * 16 + l15][ks * 32 + g * 8];
                bacc[rt] = __builtin_amdgcn_mfma_f32_16x16x32_bf16(a, wb[ks], bacc[rt], 0, 0, 0);
            }
        if (l15 < 4) {
#pragma unroll
            for (int rt = 0; rt < 4; ++rt)
#pragma unroll
                for (int r = 0; r < 4; ++r)
                    bN[l15 * 65536 + xq * 256 + y0 + wr * 64 + rt * 16 + g * 4 + r] =
                        bacc[rt][r];
        }
    }

    // ---- 4 projection matrices, barrier-free ----
    for (int wsel = 0; wsel < 4; ++wsel) {
        const unsigned short* __restrict__ W = wbf + wsel * 16384;
        f32x4 acc[4][2];
#pragma unroll
        for (int rt = 0; rt < 4; ++rt) {
            acc[rt][0] = (f32x4){0.f, 0.f, 0.f, 0.f};
            acc[rt][1] = (f32x4){0.f, 0.f, 0.f, 0.f};
        }
#pragma unroll
        for (int ks = 0; ks < 4; ++ks) {
            short8v b0 = *(const short8v*)(W + (wc * 32 + l15) * 128 + ks * 32 + g * 8);
            short8v b1 = *(const short8v*)(W + (wc * 32 + 16 + l15) * 128 + ks * 32 + g * 8);
#pragma unroll
            for (int rt = 0; rt < 4; ++rt) {
                short8v a = *(const short8v*)&zn[wr * 64 + rt * 16 + l15][ks * 32 + g * 8];
                acc[rt][0] = __builtin_amdgcn_mfma_f32_16x16x32_bf16(a, b0, acc[rt][0], 0, 0, 0);
                acc[rt][1] = __builtin_amdgcn_mfma_f32_16x16x32_bf16(a, b1, acc[rt][1], 0, 0, 0);
            }
        }

        if (wsel == 3) {
            // sigmoid gate, fp32 head-major [h][pos][32]
#pragma unroll
            for (int ct = 0; ct < 2; ++ct) {
                float bgc = bg[wc * 32 + ct * 16 + l15];
#pragma unroll
                for (int rt = 0; rt < 4; ++rt)
#pragma unroll
                    for (int r = 0; r < 4; ++r) {
                        float val = acc[rt][ct][r] + bgc;
                        g_o[((long)wc * 65536 + p0 + wr * 64 + rt * 16 + g * 4 + r) * 32 +
                            ct * 16 + l15] = 1.0f / (1.0f + __expf(-val));
                    }
            }
        } else if (wsel == 2) {
            // V: stage TRANSPOSED (wstg[d][key_local]) then coalesced copy-out
#pragma unroll
            for (int pair = 0; pair < 2; ++pair) {
#pragma unroll
                for (int rt2 = 0; rt2 < 2; ++rt2)
#pragma unroll
                    for (int ct = 0; ct < 2; ++ct)
#pragma unroll
                        for (int r = 0; r < 4; ++r)
                            wstg[wave][ct * 16 + l15][rt2 * 16 + g * 4 + r] =
                                f2bf(acc[pair * 2 + rt2][ct][r]);
#pragma unroll
                for (int e = 0; e < 4; ++e) {
                    int idx = e * 64 + lane;
                    int d = idx >> 3, k4 = idx & 7;
                    short4 sv = *(const short4*)&wstg[wave][d][k4 * 4];
                    *(short4*)(vt_o + (((long)wc * 256 + xq) * 32 + d) * 256 +
                               y0 + wr * 64 + pair * 32 + k4 * 4) = sv;
                }
            }
        } else {
            unsigned short* __restrict__ O = (wsel == 0) ? q_o : k_o;
#pragma unroll
            for (int pair = 0; pair < 2; ++pair) {
#pragma unroll
                for (int rt2 = 0; rt2 < 2; ++rt2)
#pragma unroll
                    for (int ct = 0; ct < 2; ++ct)
#pragma unroll
                        for (int r = 0; r < 4; ++r)
                            wstg[wave][rt2 * 16 + g * 4 + r][ct * 16 + l15] =
                                f2bf(acc[pair * 2 + rt2][ct][r]);
#pragma unroll
                for (int ps = 0; ps < 2; ++ps) {
                    int idx = ps * 64 + lane;
                    int lr = idx >> 2, ch = (idx & 3) * 8;
                    short8v vv = *(const short8v*)&wstg[wave][lr][ch];
                    *(short8v*)(O + ((long)wc * 65536 + p0 + wr * 64 + pair * 32 + lr) * 32 + ch) = vv;
                }
            }
        }
    }
}

// ---------------------------------------------------------------------------
// KB: attention for one (head h, row i). K A-frags and V^T B-frags live in
// REGISTERS (loaded once from global, reused by all 4 q-tiles). No K/V LDS.
// Fast path (whole block unmasked): softmax = exp(acc) directly (shift-
// invariant; logits are O(1)). Slow path: mask as additive bias, masked rows
// get p==1 for all keys -> exact uniform 1/256. P packed via pk2.
// ---------------------------------------------------------------------------
__global__ __launch_bounds__(256, 2) void k_attn_mfma(
    const unsigned short* __restrict__ q_ws, const unsigned short* __restrict__ k_ws,
    const unsigned short* __restrict__ vt_ws, const float* __restrict__ g_ws,
    const float* __restrict__ bN, const float* __restrict__ pm,
    float* __restrict__ o_ws)
{
    __shared__ __align__(16) short Psh[4][16][264];   // per-wave P
    __shared__ float pmsh[256];
    __shared__ float madd[256];

    const int tid  = threadIdx.x;
    const int lane = tid & 63;
    const int wave = tid >> 6;
    const int g    = lane >> 4;
    const int l15  = lane & 15;
    const int h = blockIdx.x & 3;
    const int i = blockIdx.x >> 2;
    const long hbase  = ((long)h * 65536 + (long)i * 256) * 32;  // q/k head-major
    const long vtbase = ((long)h * 256 + i) * 8192;              // VT [d][k]

    {
        float pv = pm[i * 256 + tid];
        pmsh[tid] = pv;
        madd[tid] = (pv > 0.5f) ? 0.0f : -1e9f;
    }
    __syncthreads();

    bool ok4 = true;
#pragma unroll
    for (int e = 0; e < 4; ++e) ok4 = ok4 && (pmsh[lane * 4 + e] > 0.5f);
    const bool allok = __all(ok4);   // block-uniform (same data every wave)

    // K A-fragments (16) and V^T B-fragments (16), q-tile-invariant
    short8v ak[16];
#pragma unroll
    for (int kt = 0; kt < 16; ++kt)
        ak[kt] = *(const short8v*)(k_ws + hbase + (long)(kt * 16 + l15) * 32 + g * 8);
    short8v bv[8][2];
#pragma unroll
    for (int ch = 0; ch < 8; ++ch)
#pragma unroll
        for (int dt = 0; dt < 2; ++dt)
            bv[ch][dt] = *(const short8v*)(vt_ws + vtbase +
                                           (long)(dt * 16 + l15) * 256 + ch * 32 + g * 8);

    const float* bbase = bN + h * 65536;

    for (int qi = 0; qi < 4; ++qi) {
        const int q0 = (wave * 4 + qi) * 16;
        const int ql = q0 + l15;
        short8v bq = *(const short8v*)(q_ws + hbase + (long)ql * 32 + g * 8);
        const bool rowok = pmsh[ql] > 0.5f;

        float lsum = 0.f;
#pragma unroll
        for (int hf = 0; hf < 2; ++hf) {
            f32x4 acc[8];
#pragma unroll
            for (int k8 = 0; k8 < 8; ++k8) {
                int kt = hf * 8 + k8;
                f32x4 cini = *(const f32x4*)(bbase + ql * 256 + kt * 16 + g * 4);
                acc[k8] = __builtin_amdgcn_mfma_f32_16x16x32_bf16(ak[kt], bq, cini, 0, 0, 0);
            }
            if (allok) {
#pragma unroll
                for (int k8 = 0; k8 < 8; ++k8) {
                    int kt = hf * 8 + k8;
                    float p0 = __expf(acc[k8][0]);
                    float p1 = __expf(acc[k8][1]);
                    float p2 = __expf(acc[k8][2]);
                    float p3 = __expf(acc[k8][3]);
                    lsum += (p0 + p1) + (p2 + p3);
                    uint2 pw;
                    pw.x = pk2(p0, p1);
                    pw.y = pk2(p2, p3);
                    *(uint2*)&Psh[wave][l15][kt * 16 + g * 4] = pw;
                }
            } else {
#pragma unroll
                for (int k8 = 0; k8 < 8; ++k8) {
                    int kt = hf * 8 + k8;
                    f32x4 ma = *(const f32x4*)&madd[kt * 16 + g * 4];
                    float p0 = __expf(rowok ? acc[k8][0] + ma[0] : 0.0f);
                    float p1 = __expf(rowok ? acc[k8][1] + ma[1] : 0.0f);
                    float p2 = __expf(rowok ? acc[k8][2] + ma[2] : 0.0f);
                    float p3 = __expf(rowok ? acc[k8][3] + ma[3] : 0.0f);
                    lsum += (p0 + p1) + (p2 + p3);
                    uint2 pw;
                    pw.x = pk2(p0, p1);
                    pw.y = pk2(p2, p3);
                    *(uint2*)&Psh[wave][l15][kt * 16 + g * 4] = pw;
                }
            }
        }
        lsum += __shfl_xor(lsum, 16);
        lsum += __shfl_xor(lsum, 32);
        const float linv_own = 1.0f / lsum;

        asm volatile("s_waitcnt lgkmcnt(0)" ::: "memory");

        f32x4 o0 = {0.f, 0.f, 0.f, 0.f}, o1 = {0.f, 0.f, 0.f, 0.f};
#pragma unroll
        for (int ch = 0; ch < 8; ++ch) {
            short8v ap = *(const short8v*)&Psh[wave][l15][ch * 32 + g * 8];
            o0 = __builtin_amdgcn_mfma_f32_16x16x32_bf16(ap, bv[ch][0], o0, 0, 0, 0);
            o1 = __builtin_amdgcn_mfma_f32_16x16x32_bf16(ap, bv[ch][1], o1, 0, 0, 0);
        }

#pragma unroll
        for (int r = 0; r < 4; ++r) {
            int qrow = g * 4 + r;
            float linv = __shfl(linv_own, qrow);
            long grow = hbase + (long)(q0 + qrow) * 32;
            long orow = (long)(i * 256 + q0 + qrow) * 128 + h * 32;
            float gv0 = g_ws[grow + l15];
            float gv1 = g_ws[grow + 16 + l15];
            o_ws[orow + l15]      = o0[r] * linv * gv0;
            o_ws[orow + 16 + l15] = o1[r] * linv * gv1;
        }
    }
}

// ---------------------------------------------------------------------------
// KC: out = o @ Wo^T + bo via pre-split hi/lo bf16 MFMA (fp32-accurate).
// 512 threads, wave tile 64x32, no LDS, no barriers.
// ---------------------------------------------------------------------------
__global__ __launch_bounds__(512, 4) void k_outproj(
    const float* __restrict__ og, const unsigned short* __restrict__ wohi,
    const unsigned short* __restrict__ wolo, const float* __restrict__ bo,
    float* __restrict__ out)
{
    const int tid  = threadIdx.x;
    const int lane = tid & 63;
    const int wave = tid >> 6;
    const int l15  = lane & 15;
    const int g    = lane >> 4;
    const int wr   = wave >> 2;
    const int wc   = wave & 3;
    const long p0  = (long)blockIdx.x * 128;

    f32x4 acc[4][2];
#pragma unroll
    for (int rt = 0; rt < 4; ++rt) {
        acc[rt][0] = (f32x4){0.f, 0.f, 0.f, 0.f};
        acc[rt][1] = (f32x4){0.f, 0.f, 0.f, 0.f};
    }

#pragma unroll
    for (int ks = 0; ks < 4; ++ks) {
        const int wof = ks * 32 + g * 8;
        short8v bh0 = *(const short8v*)(wohi + (wc * 32 + l15) * 128 + wof);
        short8v bh1 = *(const short8v*)(wohi + (wc * 32 + 16 + l15) * 128 + wof);
        short8v bl0 = *(const short8v*)(wolo + (wc * 32 + l15) * 128 + wof);
        short8v bl1 = *(const short8v*)(wolo + (wc * 32 + 16 + l15) * 128 + wof);
#pragma unroll
        for (int rt = 0; rt < 4; ++rt) {
            const float* ap = og + (p0 + wr * 64 + rt * 16 + l15) * 128 + ks * 32 + g * 8;
            float4 x0 = *(const float4*)ap;
            float4 x1 = *(const float4*)(ap + 4);
            float xs[8] = {x0.x, x0.y, x0.z, x0.w, x1.x, x1.y, x1.z, x1.w};
            short8v ah, al;
#pragma unroll
            for (int e = 0; e < 8; ++e) {
                short hv = f2bf(xs[e]);
                ah[e] = hv;
                al[e] = f2bf(xs[e] - bf2f(hv));
            }
            acc[rt][0] = __builtin_amdgcn_mfma_f32_16x16x32_bf16(ah, bh0, acc[rt][0], 0, 0, 0);
            acc[rt][0] = __builtin_amdgcn_mfma_f32_16x16x32_bf16(ah, bl0, acc[rt][0], 0, 0, 0);
            acc[rt][0] = __builtin_amdgcn_mfma_f32_16x16x32_bf16(al, bh0, acc[rt][0], 0, 0, 0);
            acc[rt][1] = __builtin_amdgcn_mfma_f32_16x16x32_bf16(ah, bh1, acc[rt][1], 0, 0, 0);
            acc[rt][1] = __builtin_amdgcn_mfma_f32_16x16x32_bf16(ah, bl1, acc[rt][1], 0, 0, 0);
            acc[rt][1] = __builtin_amdgcn_mfma_f32_16x16x32_bf16(al, bh1, acc[rt][1], 0, 0, 0);
        }
    }

#pragma unroll
    for (int ct = 0; ct < 2; ++ct) {
        float bv = bo[wc * 32 + ct * 16 + l15];
#pragma unroll
        for (int rt = 0; rt < 4; ++rt)
#pragma unroll
            for (int r = 0; r < 4; ++r)
                out[(p0 + wr * 64 + rt * 16 + g * 4 + r) * 128 +
                    wc * 32 + ct * 16 + l15] = acc[rt][ct][r] + bv;
    }
}

// ---------------------------------------------------------------------------
extern "C" void kernel_launch(void* const* d_in, const int* in_sizes, int n_in,
                              void* d_out, int out_size, void* d_ws, size_t ws_size,
                              hipStream_t stream) {
    const float* z   = (const float*)d_in[0];
    const float* pm  = (const float*)d_in[1];
    const float* lnw = (const float*)d_in[2];
    const float* lnb = (const float*)d_in[3];
    const float* Wq  = (const float*)d_in[4];
    const float* Wk  = (const float*)d_in[5];
    const float* Wv  = (const float*)d_in[6];
    const float* Wb  = (const float*)d_in[7];
    const float* Wg  = (const float*)d_in[8];
    const float* bg  = (const float*)d_in[9];
    const float* Wo  = (const float*)d_in[10];
    const float* bo  = (const float*)d_in[11];
    float* out = (float*)d_out;

    unsigned short* wsS  = (unsigned short*)d_ws;
    unsigned short* wbf  = wsS;                   // 65536  (4x128x128 bf16)
    unsigned short* wbbf = wsS + 65536;           // 512
    unsigned short* wohi = wsS + 66048;           // 16384
    unsigned short* wolo = wsS + 82432;           // 16384
    unsigned short* qb   = wsS + 98816;           // 8388608 bf16 [4][65536][32]
    unsigned short* kb   = qb + 8388608;          // 8388608 bf16 [4][65536][32]
    unsigned short* vtb  = kb + 8388608;          // 8388608 bf16 [4][256][32][256]
    float* fbase = (float*)(wsS + 98816 + 3 * 8388608);
    float* gws = fbase;                           // 8388608 fp32 [4][65536][32]
    float* bNw = gws + 8388608;                   // 262144 fp32 [4][256][256]
    float* ows = bNw + 262144;                    // 8388608 fp32 [65536][128]

    k_wprep<<<322, 256, 0, stream>>>(Wq, Wk, Wv, Wg, Wb, Wo, wbf, wbbf, wohi, wolo);
    k_lnproj<<<512, 512, 0, stream>>>(z, lnw, lnb, wbf, wbbf, bg, qb, kb, vtb, gws, bNw);
    k_attn_mfma<<<1024, 256, 0, stream>>>(qb, kb, vtb, gws, bNw, pm, ows);
    k_outproj<<<512, 512, 0, stream>>>(ows, wohi, wolo, bo, out);
}

// Round 8
// 118.823 us; speedup vs baseline: 1.0310x; 1.0310x over previous
//
#include <hip/hip_runtime.h>
#include <hip/hip_bf16.h>

#define ATT_SCALE 0.17677669529663687f   // 1/sqrt(32)

typedef __attribute__((ext_vector_type(8))) short short8v;
typedef __attribute__((ext_vector_type(4))) float f32x4;

__device__ __forceinline__ short f2bf(float f) {
    unsigned u = __builtin_bit_cast(unsigned, f);
    u = u + 0x7fffu + ((u >> 16) & 1u);   // RNE
    return (short)(u >> 16);
}
__device__ __forceinline__ float bf2f(short s) {
    unsigned u = ((unsigned)(unsigned short)s) << 16;
    return __builtin_bit_cast(float, u);
}
__device__ __forceinline__ unsigned pk2(float lo, float hi) {
    return (unsigned)(unsigned short)f2bf(lo) |
           ((unsigned)(unsigned short)f2bf(hi) << 16);
}
__device__ __forceinline__ float lo16f(unsigned w) {
    return __builtin_bit_cast(float, w << 16);
}
__device__ __forceinline__ float hi16f(unsigned w) {
    return __builtin_bit_cast(float, w & 0xffff0000u);
}

// ---------------------------------------------------------------------------
// K0: one-time weight conversion. wbf = bf16{Wq*scale, Wk, Wv, Wg};
// wbbf = bf16 Wb; Wo -> hi/lo bf16 split.
// ---------------------------------------------------------------------------
__global__ __launch_bounds__(256) void k_wprep(
    const float* __restrict__ Wq, const float* __restrict__ Wk,
    const float* __restrict__ Wv, const float* __restrict__ Wg,
    const float* __restrict__ Wb, const float* __restrict__ Wo,
    unsigned short* __restrict__ wbf, unsigned short* __restrict__ wbbf,
    unsigned short* __restrict__ wohi, unsigned short* __restrict__ wolo)
{
    int idx = blockIdx.x * 256 + threadIdx.x;
    if (idx < 65536) {
        int m = idx >> 14, e = idx & 16383;
        float v;
        if (m == 0)      v = Wq[e] * ATT_SCALE;
        else if (m == 1) v = Wk[e];
        else if (m == 2) v = Wv[e];
        else             v = Wg[e];
        wbf[idx] = (unsigned short)f2bf(v);
    } else if (idx < 66048) {
        int e = idx - 65536;
        wbbf[e] = (unsigned short)f2bf(Wb[e]);
    } else if (idx < 82432) {
        int e = idx - 66048;
        float w = Wo[e];
        short hv = f2bf(w);
        wohi[e] = (unsigned short)hv;
        wolo[e] = (unsigned short)f2bf(w - bf2f(hv));
    }
}

// ---------------------------------------------------------------------------
// KA: LN + projections + bias. 512 threads = 8 waves, block = 128 positions.
// Wave tile 64 rows x 32 cols; wc (0..3) == head. One barrier total.
// q/k written bf16 head-major [h][pos][32]; V written TRANSPOSED bf16
// VT[h][x][d=32][y=256]. g fp32 head-major. bias bf16 natural [h][j][k].
// ---------------------------------------------------------------------------
__global__ __launch_bounds__(512, 4) void k_lnproj(
    const float* __restrict__ z, const float* __restrict__ lnw,
    const float* __restrict__ lnb,
    const unsigned short* __restrict__ wbf, const unsigned short* __restrict__ wbbf,
    const float* __restrict__ bg,
    unsigned short* __restrict__ q_o, unsigned short* __restrict__ k_o,
    unsigned short* __restrict__ vt_o, float* __restrict__ g_o,
    unsigned short* __restrict__ bbf)
{
    __shared__ __align__(16) short zn[128][136];       // 34.8 KB, persists
    __shared__ __align__(16) short wstg[8][32][40];    // 20.5 KB, wave-private

    const int tid  = threadIdx.x;
    const int lane = tid & 63;
    const int wave = tid >> 6;
    const int l15  = lane & 15;
    const int g    = lane >> 4;
    const int wr   = wave >> 2;       // row half (0..1)
    const int wc   = wave & 3;        // col quarter == head (0..3)
    const long p0  = (long)blockIdx.x * 128;
    const int xq   = (int)(p0 >> 8);
    const int y0   = (int)(p0 & 255);

    // ---- LN: thread = (row, quarter) ----
    {
        const int r = tid >> 2, q4 = tid & 3;
        const float* zrow = z + (p0 + r) * 128 + q4 * 32;
        float4 xv[8];
        float s1 = 0.f, s2 = 0.f;
#pragma unroll
        for (int m = 0; m < 8; ++m) {
            xv[m] = *(const float4*)(zrow + m * 4);
            s1 += xv[m].x + xv[m].y + xv[m].z + xv[m].w;
            s2 += xv[m].x * xv[m].x + xv[m].y * xv[m].y +
                  xv[m].z * xv[m].z + xv[m].w * xv[m].w;
        }
        s1 += __shfl_xor(s1, 1); s2 += __shfl_xor(s2, 1);
        s1 += __shfl_xor(s1, 2); s2 += __shfl_xor(s2, 2);
        float mu  = s1 * 0.0078125f;
        float inv = rsqrtf(s2 * 0.0078125f - mu * mu + 1e-5f);
#pragma unroll
        for (int mm = 0; mm < 4; ++mm) {
            float4 a = xv[2 * mm], b = xv[2 * mm + 1];
            const float* wp = lnw + q4 * 32 + mm * 8;
            const float* bp = lnb + q4 * 32 + mm * 8;
            float4 w0 = *(const float4*)wp, w1 = *(const float4*)(wp + 4);
            float4 b0 = *(const float4*)bp, b1 = *(const float4*)(bp + 4);
            uint4 uu;
            uu.x = pk2((a.x - mu) * inv * w0.x + b0.x, (a.y - mu) * inv * w0.y + b0.y);
            uu.y = pk2((a.z - mu) * inv * w0.z + b0.z, (a.w - mu) * inv * w0.w + b0.w);
            uu.z = pk2((b.x - mu) * inv * w1.x + b1.x, (b.y - mu) * inv * w1.y + b1.y);
            uu.w = pk2((b.z - mu) * inv * w1.z + b1.z, (b.w - mu) * inv * w1.w + b1.w);
            *(uint4*)&zn[r][q4 * 32 + mm * 8] = uu;
        }
    }
    __syncthreads();   // the only block-wide barrier

    // ---- pair bias (waves with wc==0; lanes l15<4 write head l15), bf16 ----
    if (wc == 0) {
        const unsigned short* wbp = wbbf + (l15 & 3) * 128;
        short8v wb[4];
#pragma unroll
        for (int ks = 0; ks < 4; ++ks)
            wb[ks] = *(const short8v*)(wbp + ks * 32 + g * 8);
        f32x4 bacc[4];
#pragma unroll
        for (int rt = 0; rt < 4; ++rt) bacc[rt] = (f32x4){0.f, 0.f, 0.f, 0.f};
#pragma unroll
        for (int ks = 0; ks < 4; ++ks)
#pragma unroll
            for (int rt = 0; rt < 4; ++rt) {
                short8v a = *(const short8v*)&zn[wr * 64 + rt * 16 + l15][ks * 32 + g * 8];
                bacc[rt] = __builtin_amdgcn_mfma_f32_16x16x32_bf16(a, wb[ks], bacc[rt], 0, 0, 0);
            }
        if (l15 < 4) {
#pragma unroll
            for (int rt = 0; rt < 4; ++rt) {
                uint2 w;
                w.x = pk2(bacc[rt][0], bacc[rt][1]);
                w.y = pk2(bacc[rt][2], bacc[rt][3]);
                *(uint2*)(bbf + (long)l15 * 65536 + xq * 256 + y0 +
                          wr * 64 + rt * 16 + g * 4) = w;
            }
        }
    }

    // ---- 4 projection matrices, barrier-free ----
    for (int wsel = 0; wsel < 4; ++wsel) {
        const unsigned short* __restrict__ W = wbf + wsel * 16384;
        f32x4 acc[4][2];
#pragma unroll
        for (int rt = 0; rt < 4; ++rt) {
            acc[rt][0] = (f32x4){0.f, 0.f, 0.f, 0.f};
            acc[rt][1] = (f32x4){0.f, 0.f, 0.f, 0.f};
        }
#pragma unroll
        for (int ks = 0; ks < 4; ++ks) {
            short8v b0 = *(const short8v*)(W + (wc * 32 + l15) * 128 + ks * 32 + g * 8);
            short8v b1 = *(const short8v*)(W + (wc * 32 + 16 + l15) * 128 + ks * 32 + g * 8);
#pragma unroll
            for (int rt = 0; rt < 4; ++rt) {
                short8v a = *(const short8v*)&zn[wr * 64 + rt * 16 + l15][ks * 32 + g * 8];
                acc[rt][0] = __builtin_amdgcn_mfma_f32_16x16x32_bf16(a, b0, acc[rt][0], 0, 0, 0);
                acc[rt][1] = __builtin_amdgcn_mfma_f32_16x16x32_bf16(a, b1, acc[rt][1], 0, 0, 0);
            }
        }

        if (wsel == 3) {
            // sigmoid gate, fp32 head-major [h][pos][32]
#pragma unroll
            for (int ct = 0; ct < 2; ++ct) {
                float bgc = bg[wc * 32 + ct * 16 + l15];
#pragma unroll
                for (int rt = 0; rt < 4; ++rt)
#pragma unroll
                    for (int r = 0; r < 4; ++r) {
                        float val = acc[rt][ct][r] + bgc;
                        g_o[((long)wc * 65536 + p0 + wr * 64 + rt * 16 + g * 4 + r) * 32 +
                            ct * 16 + l15] = 1.0f / (1.0f + __expf(-val));
                    }
            }
        } else if (wsel == 2) {
            // V: stage TRANSPOSED (wstg[d][key_local]) then coalesced copy-out
#pragma unroll
            for (int pair = 0; pair < 2; ++pair) {
#pragma unroll
                for (int rt2 = 0; rt2 < 2; ++rt2)
#pragma unroll
                    for (int ct = 0; ct < 2; ++ct)
#pragma unroll
                        for (int r = 0; r < 4; ++r)
                            wstg[wave][ct * 16 + l15][rt2 * 16 + g * 4 + r] =
                                f2bf(acc[pair * 2 + rt2][ct][r]);
#pragma unroll
                for (int e = 0; e < 4; ++e) {
                    int idx = e * 64 + lane;
                    int d = idx >> 3, k4 = idx & 7;
                    short4 sv = *(const short4*)&wstg[wave][d][k4 * 4];
                    *(short4*)(vt_o + (((long)wc * 256 + xq) * 32 + d) * 256 +
                               y0 + wr * 64 + pair * 32 + k4 * 4) = sv;
                }
            }
        } else {
            unsigned short* __restrict__ O = (wsel == 0) ? q_o : k_o;
#pragma unroll
            for (int pair = 0; pair < 2; ++pair) {
#pragma unroll
                for (int rt2 = 0; rt2 < 2; ++rt2)
#pragma unroll
                    for (int ct = 0; ct < 2; ++ct)
#pragma unroll
                        for (int r = 0; r < 4; ++r)
                            wstg[wave][rt2 * 16 + g * 4 + r][ct * 16 + l15] =
                                f2bf(acc[pair * 2 + rt2][ct][r]);
#pragma unroll
                for (int ps = 0; ps < 2; ++ps) {
                    int idx = ps * 64 + lane;
                    int lr = idx >> 2, ch = (idx & 3) * 8;
                    short8v vv = *(const short8v*)&wstg[wave][lr][ch];
                    *(short8v*)(O + ((long)wc * 65536 + p0 + wr * 64 + pair * 32 + lr) * 32 + ch) = vv;
                }
            }
        }
    }
}

// ---------------------------------------------------------------------------
// KB: attention for one (head h, row i). K and pre-transposed V^T staged in
// LDS via contiguous bf16 copies (no conversion, no transpose conflicts).
// QK^T with C=0; bf16 bias loaded decoupled (uint2) and added pre-exp.
// Fast path: softmax = exp(s) (shift-invariant, O(1) logits). Output written
// pre-split hi/lo bf16 for the outproj MFMA.
// ---------------------------------------------------------------------------
__global__ __launch_bounds__(256, 2) void k_attn_mfma(
    const unsigned short* __restrict__ q_ws, const unsigned short* __restrict__ k_ws,
    const unsigned short* __restrict__ vt_ws, const float* __restrict__ g_ws,
    const unsigned short* __restrict__ bbf, const float* __restrict__ pm,
    unsigned short* __restrict__ ohi, unsigned short* __restrict__ olo)
{
    __shared__ __align__(16) short Ksh[256][40];      // 20.5 KB
    __shared__ __align__(16) short VTsh[32][264];     // 16.9 KB
    __shared__ __align__(16) short Psh[4][16][264];   // 33.8 KB
    __shared__ float pmsh[256];
    __shared__ float madd[256];

    const int tid  = threadIdx.x;
    const int lane = tid & 63;
    const int wave = tid >> 6;
    const int g    = lane >> 4;
    const int l15  = lane & 15;
    const int h = blockIdx.x & 3;
    const int i = blockIdx.x >> 2;
    const long hbase  = ((long)h * 65536 + (long)i * 256) * 32;  // q/k head-major
    const long vtbase = ((long)h * 256 + i) * 8192;              // VT [d][k]

    {
        float pv = pm[i * 256 + tid];
        pmsh[tid] = pv;
        madd[tid] = (pv > 0.5f) ? 0.0f : -1e9f;
    }
    // stage K (contiguous) and VT (contiguous, already transposed)
#pragma unroll
    for (int pass = 0; pass < 4; ++pass) {
        int idx = pass * 256 + tid;          // 0..1023
        int r = idx >> 2, c8 = (idx & 3) * 8;
        *(short8v*)&Ksh[r][c8] = *(const short8v*)(k_ws + hbase + idx * 8);
        int d = idx >> 5, c = (idx & 31) * 8;
        *(short8v*)&VTsh[d][c] = *(const short8v*)(vt_ws + vtbase + idx * 8);
    }
    __syncthreads();

    bool ok4 = true;
#pragma unroll
    for (int e = 0; e < 4; ++e) ok4 = ok4 && (pmsh[lane * 4 + e] > 0.5f);
    const bool allok = __all(ok4);

    const unsigned short* brow_base = bbf + (long)h * 65536;

    for (int qi = 0; qi < 4; ++qi) {
        const int q0 = (wave * 4 + qi) * 16;
        const int ql = q0 + l15;
        short8v bq = *(const short8v*)(q_ws + hbase + (long)ql * 32 + g * 8);
        const bool rowok = pmsh[ql] > 0.5f;

        // QK^T (C = 0)
        f32x4 acc[16];
#pragma unroll
        for (int kt = 0; kt < 16; ++kt) {
            short8v ak = *(const short8v*)&Ksh[kt * 16 + l15][g * 8];
            acc[kt] = __builtin_amdgcn_mfma_f32_16x16x32_bf16(
                ak, bq, (f32x4){0.f, 0.f, 0.f, 0.f}, 0, 0, 0);
        }

        // bias loads (independent of MFMA chain)
        uint2 bw[16];
#pragma unroll
        for (int kt = 0; kt < 16; ++kt)
            bw[kt] = *(const uint2*)(brow_base + (long)ql * 256 + kt * 16 + g * 4);

        float lsum = 0.f;
        if (allok) {
#pragma unroll
            for (int kt = 0; kt < 16; ++kt) {
                float p0 = __expf(acc[kt][0] + lo16f(bw[kt].x));
                float p1 = __expf(acc[kt][1] + hi16f(bw[kt].x));
                float p2 = __expf(acc[kt][2] + lo16f(bw[kt].y));
                float p3 = __expf(acc[kt][3] + hi16f(bw[kt].y));
                lsum += (p0 + p1) + (p2 + p3);
                uint2 pw;
                pw.x = pk2(p0, p1);
                pw.y = pk2(p2, p3);
                *(uint2*)&Psh[wave][l15][kt * 16 + g * 4] = pw;
            }
        } else {
#pragma unroll
            for (int kt = 0; kt < 16; ++kt) {
                f32x4 ma = *(const f32x4*)&madd[kt * 16 + g * 4];
                float p0 = __expf(rowok ? acc[kt][0] + lo16f(bw[kt].x) + ma[0] : 0.0f);
                float p1 = __expf(rowok ? acc[kt][1] + hi16f(bw[kt].x) + ma[1] : 0.0f);
                float p2 = __expf(rowok ? acc[kt][2] + lo16f(bw[kt].y) + ma[2] : 0.0f);
                float p3 = __expf(rowok ? acc[kt][3] + hi16f(bw[kt].y) + ma[3] : 0.0f);
                lsum += (p0 + p1) + (p2 + p3);
                uint2 pw;
                pw.x = pk2(p0, p1);
                pw.y = pk2(p2, p3);
                *(uint2*)&Psh[wave][l15][kt * 16 + g * 4] = pw;
            }
        }
        lsum += __shfl_xor(lsum, 16);
        lsum += __shfl_xor(lsum, 32);
        const float linv_own = 1.0f / lsum;

        asm volatile("s_waitcnt lgkmcnt(0)" ::: "memory");

        f32x4 o0 = {0.f, 0.f, 0.f, 0.f}, o1 = {0.f, 0.f, 0.f, 0.f};
#pragma unroll
        for (int ch = 0; ch < 8; ++ch) {
            short8v ap  = *(const short8v*)&Psh[wave][l15][ch * 32 + g * 8];
            short8v bv0 = *(const short8v*)&VTsh[l15][ch * 32 + g * 8];
            short8v bv1 = *(const short8v*)&VTsh[16 + l15][ch * 32 + g * 8];
            o0 = __builtin_amdgcn_mfma_f32_16x16x32_bf16(ap, bv0, o0, 0, 0, 0);
            o1 = __builtin_amdgcn_mfma_f32_16x16x32_bf16(ap, bv1, o1, 0, 0, 0);
        }

        // epilogue: normalize, gate, hi/lo split, store bf16
#pragma unroll
        for (int r = 0; r < 4; ++r) {
            int qrow = g * 4 + r;
            float linv = __shfl(linv_own, qrow);
            long grow = hbase + (long)(q0 + qrow) * 32;
            long orow = (long)(i * 256 + q0 + qrow) * 128 + h * 32;
            float v0 = o0[r] * linv * g_ws[grow + l15];
            float v1 = o1[r] * linv * g_ws[grow + 16 + l15];
            short h0 = f2bf(v0), h1 = f2bf(v1);
            ohi[orow + l15]      = (unsigned short)h0;
            ohi[orow + 16 + l15] = (unsigned short)h1;
            olo[orow + l15]      = (unsigned short)f2bf(v0 - bf2f(h0));
            olo[orow + 16 + l15] = (unsigned short)f2bf(v1 - bf2f(h1));
        }
    }
}

// ---------------------------------------------------------------------------
// KC: out = o @ Wo^T + bo. o arrives pre-split hi/lo bf16 -> pure loads+MFMA
// (3-term hi/lo product, fp32-accurate). 512 threads, no LDS, no barriers.
// ---------------------------------------------------------------------------
__global__ __launch_bounds__(512, 4) void k_outproj(
    const unsigned short* __restrict__ ohi, const unsigned short* __restrict__ olo,
    const unsigned short* __restrict__ wohi, const unsigned short* __restrict__ wolo,
    const float* __restrict__ bo, float* __restrict__ out)
{
    const int tid  = threadIdx.x;
    const int lane = tid & 63;
    const int wave = tid >> 6;
    const int l15  = lane & 15;
    const int g    = lane >> 4;
    const int wr   = wave >> 2;
    const int wc   = wave & 3;
    const long p0  = (long)blockIdx.x * 128;

    f32x4 acc[4][2];
#pragma unroll
    for (int rt = 0; rt < 4; ++rt) {
        acc[rt][0] = (f32x4){0.f, 0.f, 0.f, 0.f};
        acc[rt][1] = (f32x4){0.f, 0.f, 0.f, 0.f};
    }

#pragma unroll
    for (int ks = 0; ks < 4; ++ks) {
        const int wof = ks * 32 + g * 8;
        short8v bh0 = *(const short8v*)(wohi + (wc * 32 + l15) * 128 + wof);
        short8v bh1 = *(const short8v*)(wohi + (wc * 32 + 16 + l15) * 128 + wof);
        short8v bl0 = *(const short8v*)(wolo + (wc * 32 + l15) * 128 + wof);
        short8v bl1 = *(const short8v*)(wolo + (wc * 32 + 16 + l15) * 128 + wof);
#pragma unroll
        for (int rt = 0; rt < 4; ++rt) {
            long aoff = (p0 + wr * 64 + rt * 16 + l15) * 128 + ks * 32 + g * 8;
            short8v ah = *(const short8v*)(ohi + aoff);
            short8v al = *(const short8v*)(olo + aoff);
            acc[rt][0] = __builtin_amdgcn_mfma_f32_16x16x32_bf16(ah, bh0, acc[rt][0], 0, 0, 0);
            acc[rt][0] = __builtin_amdgcn_mfma_f32_16x16x32_bf16(ah, bl0, acc[rt][0], 0, 0, 0);
            acc[rt][0] = __builtin_amdgcn_mfma_f32_16x16x32_bf16(al, bh0, acc[rt][0], 0, 0, 0);
            acc[rt][1] = __builtin_amdgcn_mfma_f32_16x16x32_bf16(ah, bh1, acc[rt][1], 0, 0, 0);
            acc[rt][1] = __builtin_amdgcn_mfma_f32_16x16x32_bf16(ah, bl1, acc[rt][1], 0, 0, 0);
            acc[rt][1] = __builtin_amdgcn_mfma_f32_16x16x32_bf16(al, bh1, acc[rt][1], 0, 0, 0);
        }
    }

#pragma unroll
    for (int ct = 0; ct < 2; ++ct) {
        float bv = bo[wc * 32 + ct * 16 + l15];
#pragma unroll
        for (int rt = 0; rt < 4; ++rt)
#pragma unroll
            for (int r = 0; r < 4; ++r)
                out[(p0 + wr * 64 + rt * 16 + g * 4 + r) * 128 +
                    wc * 32 + ct * 16 + l15] = acc[rt][ct][r] + bv;
    }
}

// ---------------------------------------------------------------------------
extern "C" void kernel_launch(void* const* d_in, const int* in_sizes, int n_in,
                              void* d_out, int out_size, void* d_ws, size_t ws_size,
                              hipStream_t stream) {
    const float* z   = (const float*)d_in[0];
    const float* pm  = (const float*)d_in[1];
    const float* lnw = (const float*)d_in[2];
    const float* lnb = (const float*)d_in[3];
    const float* Wq  = (const float*)d_in[4];
    const float* Wk  = (const float*)d_in[5];
    const float* Wv  = (const float*)d_in[6];
    const float* Wb  = (const float*)d_in[7];
    const float* Wg  = (const float*)d_in[8];
    const float* bg  = (const float*)d_in[9];
    const float* Wo  = (const float*)d_in[10];
    const float* bo  = (const float*)d_in[11];
    float* out = (float*)d_out;

    unsigned short* wsS  = (unsigned short*)d_ws;
    unsigned short* wbf  = wsS;                   // 65536
    unsigned short* wbbf = wsS + 65536;           // 512
    unsigned short* wohi = wsS + 66048;           // 16384
    unsigned short* wolo = wsS + 82432;           // 16384
    unsigned short* bbf  = wsS + 98816;           // 262144 bf16 [4][256][256]
    unsigned short* qb   = wsS + 360960;          // 8388608 bf16 [4][65536][32]
    unsigned short* kb   = qb + 8388608;
    unsigned short* vtb  = kb + 8388608;          // [4][256][32][256]
    unsigned short* ohiw = vtb + 8388608;         // 8388608 bf16 [65536][128]
    unsigned short* olow = ohiw + 8388608;        // 8388608
    float* gws = (float*)(olow + 8388608);        // 8388608 fp32 [4][65536][32]

    k_wprep<<<322, 256, 0, stream>>>(Wq, Wk, Wv, Wg, Wb, Wo, wbf, wbbf, wohi, wolo);
    k_lnproj<<<512, 512, 0, stream>>>(z, lnw, lnb, wbf, wbbf, bg, qb, kb, vtb, gws, bbf);
    k_attn_mfma<<<1024, 256, 0, stream>>>(qb, kb, vtb, gws, bbf, pm, ohiw, olow);
    k_outproj<<<512, 512, 0, stream>>>(ohiw, olow, wohi, wolo, bo, out);
}